// Round 4
// baseline (126.385 us; speedup 1.0000x reference)
//
#include <hip/hip_runtime.h>
#include <math.h>

#define LAYERS  8
#define FEAT    3072
#define NCLASS  10
#define DIM     4096

typedef float v2f __attribute__((ext_vector_type(2)));
typedef float v4f __attribute__((ext_vector_type(4)));

// gray code of 5-bit value (inverse of prefix-xor); compile-time under unroll
__device__ __forceinline__ int gray5(int u) { return (u ^ (u >> 1)) & 31; }

// LDS layout: f(i) = (i>>7) + 36*(i&127) + 8*((i>>5)&3), i = psi index (12b).
// A side (i = 32*tid + r): addr = baseA + 36r   (b32, 2-way banks = free)
// B side (i = tid + 128*r): addr = baseB + r    (b128, 8/bank balanced = full BW)

__global__ __launch_bounds__(128, 4)
void qnn_kernel(const float* __restrict__ x,
                const float* __restrict__ ang,
                const float* __restrict__ W,
                const float* __restrict__ bias,
                float* __restrict__ out)
{
    __shared__ __attribute__((aligned(16))) float lds[4628];
    __shared__ float cst[96], snt[96];
    __shared__ float redp[2 * NCLASS];
    __shared__ float redss[2];

    const int tid  = threadIdx.x;       // 0..127, 2 waves per block/state
    const int lane = tid & 63;
    const int w    = tid >> 6;
    const int b    = blockIdx.x;

    if (tid < 96) { float a = ang[tid]; cst[tid] = cosf(a); snt[tid] = sinf(a); }

    // ---- load psi0, A layout: v[i] = (psi[32*tid+2i], psi[32*tid+2i+1]) ----
    v2f v[16];
    if (tid < FEAT / 32) {              // tid < 96
        const float* xr = x + (size_t)b * FEAT + 32 * tid;
#pragma unroll
        for (int j = 0; j < 8; ++j) {
            v4f f4 = *(const v4f*)(xr + 4 * j);
            v[2 * j]     = (v2f){f4.x, f4.y};
            v[2 * j + 1] = (v2f){f4.z, f4.w};
        }
    } else {
#pragma unroll
        for (int i = 0; i < 16; ++i) v[i] = (v2f){0.f, 0.f};
    }

    // ---- ||x||^2 partials (normalization deferred: circuit is linear) ----
    {
        v2f s2 = {0.f, 0.f};
#pragma unroll
        for (int i = 0; i < 16; ++i) s2 += v[i] * v[i];
        float ss = s2.x + s2.y;
#pragma unroll
        for (int o = 1; o < 64; o <<= 1) ss += __shfl_xor(ss, o, 64);
        if (lane == 0) redss[w] = ss;
    }

    // ---- address bases ----
    const int baseA = (tid >> 2) + 1160 * (tid & 3);
    const int baseB = 36 * tid + 8 * ((tid >> 5) & 3);
    int T = tid ^ (tid >> 1); T ^= T >> 2; T ^= T >> 4; T &= 127;  // px7(tid)
    const int pf    = T & 1;                                       // parity(tid)
    const int bgray = (T >> 2) + 1160 * (T & 3) + (pf ? 36 * 31 : 0);
    const int sg36  = pf ? -36 : 36;    // gray-read addr = bgray + sg36*u

    __syncthreads();   // tables + redss ready

#pragma unroll 1
    for (int l = 0; l < LAYERS; ++l) {
        const float* cl = cst + l * 12;
        const float* sl = snt + l * 12;

        // ---- A phase: index-bit 0 (comp) -> qubit 11 ----
        {
            const float c = cl[11], s = sl[11];
            const v2f c2 = {c, c}, ms = {-s, s};
#pragma unroll
            for (int i = 0; i < 16; ++i) {
                v2f a = v[i]; v2f sw = {a.y, a.x};
                v[i] = a * c2 + sw * ms;
            }
        }
        // index-bits 1..4 (array bits 0..3) -> qubits 10..7
#pragma unroll
        for (int p = 0; p < 4; ++p) {
            const float c = cl[10 - p], s = sl[10 - p];
            const v2f c2 = {c, c}, s2 = {s, s};
#pragma unroll
            for (int i0 = 0; i0 < 16; ++i0) {
                if (i0 & (1 << p)) continue;
                const int i1 = i0 | (1 << p);
                v2f a = v[i0], e = v[i1];
                v[i0] = a * c2 - e * s2;
                v[i1] = a * s2 + e * c2;
            }
        }
        // index-bit 5 (lane bit 0) -> qubit 6; index-bit 6 (lane bit 1) -> qubit 5
#pragma unroll
        for (int m = 1; m <= 2; m <<= 1) {
            const int q = (m == 1) ? 6 : 5;
            const float c  = cl[q];
            const float sp = (lane & m) ? sl[q] : -sl[q];  // v' = c*v + sp*e
            const v2f c2 = {c, c}, s2 = {sp, sp};
#pragma unroll
            for (int i = 0; i < 16; ++i) {
                v2f e;
                e.x = __shfl_xor(v[i].x, m, 64);
                e.y = __shfl_xor(v[i].y, m, 64);
                v[i] = v[i] * c2 + e * s2;
            }
        }

        // ---- A -> LDS ----
#pragma unroll
        for (int i = 0; i < 16; ++i) {
            lds[baseA + 72 * i]      = v[i].x;
            lds[baseA + 72 * i + 36] = v[i].y;
        }
        __syncthreads();

        // ---- LDS -> B (b128): vb[r] = psi[tid + 128 r] ----
#pragma unroll
        for (int k = 0; k < 8; ++k) {
            v4f q = *(const v4f*)(lds + baseB + 4 * k);
            v[2 * k]     = (v2f){q.x, q.y};
            v[2 * k + 1] = (v2f){q.z, q.w};
        }

        // ---- B phase: index-bit 7 (comp) -> qubit 4 ----
        {
            const float c = cl[4], s = sl[4];
            const v2f c2 = {c, c}, ms = {-s, s};
#pragma unroll
            for (int i = 0; i < 16; ++i) {
                v2f a = v[i]; v2f sw = {a.y, a.x};
                v[i] = a * c2 + sw * ms;
            }
        }
        // index-bits 8..11 (array bits 0..3) -> qubits 3..0
#pragma unroll
        for (int p = 0; p < 4; ++p) {
            const float c = cl[3 - p], s = sl[3 - p];
            const v2f c2 = {c, c}, s2 = {s, s};
#pragma unroll
            for (int i0 = 0; i0 < 16; ++i0) {
                if (i0 & (1 << p)) continue;
                const int i1 = i0 | (1 << p);
                v2f a = v[i0], e = v[i1];
                v[i0] = a * c2 - e * s2;
                v[i1] = a * s2 + e * c2;
            }
        }

        if (l == LAYERS - 1) break;   // Gray of last layer folds into epilogue

        // ---- B -> LDS (own addresses, b128; no barrier needed before) ----
#pragma unroll
        for (int k = 0; k < 8; ++k) {
            *(v4f*)(lds + baseB + 4 * k) =
                (v4f){v[2 * k].x, v[2 * k].y, v[2 * k + 1].x, v[2 * k + 1].y};
        }
        __syncthreads();

        // ---- LDS -> A with CNOT-cascade (Gray) perm folded:
        //      v[gray5(u)] = lds[bgray + sg36*u]  (reads f(32*px7(tid) + px5(r)^flip)) ----
#pragma unroll
        for (int u = 0; u < 32; ++u) {
            const int r = gray5(u);                 // compile-time
            const float val = lds[bgray + sg36 * u];
            if (r & 1) v[r >> 1].y = val; else v[r >> 1].x = val;
        }
        __syncthreads();   // before next layer's A-write overwrites f
    }

    // ---- epilogue ----
    // B layout: j = tid + 128 r;  g(j) = (gray7(tid)&63) + 64*(w ^ (r&1)) + 128*gray5(r)
    __syncthreads();   // all B-reads of layer 7 done before scatter clobbers buffer

    const int G   = (tid ^ (tid >> 1)) & 63;
    const int bq0 = G + 64 * w;          // r even
    const int bq1 = G + 64 * (1 - w);    // r odd

#pragma unroll
    for (int i = 0; i < 16; ++i) {
        const int ge = gray5(2 * i);
        const int go = gray5(2 * i + 1);
        lds[bq0 + 128 * ge] = v[i].x * v[i].x;   // bank = G&31: 2-way, free
        lds[bq1 + 128 * go] = v[i].y * v[i].y;
    }
    __syncthreads();

    float acc[NCLASS];
#pragma unroll
    for (int c = 0; c < NCLASS; ++c) acc[c] = 0.f;

#pragma unroll 1
    for (int k = 0; k < 8; ++k) {
        const v4f q = *(const v4f*)(lds + 4 * tid + 512 * k);   // b128 coalesced
        const float* wp = W + 4 * tid + 512 * k;
#pragma unroll
        for (int c = 0; c < NCLASS; ++c) {
            const v4f wv = *(const v4f*)(wp + c * DIM);          // dwordx4
            acc[c] += q.x * wv.x + q.y * wv.y + q.z * wv.z + q.w * wv.w;
        }
    }

#pragma unroll
    for (int c = 0; c < NCLASS; ++c) {
        float a = acc[c];
#pragma unroll
        for (int o = 1; o < 64; o <<= 1) a += __shfl_xor(a, o, 64);
        if (lane == 0) redp[w * NCLASS + c] = a;
    }
    __syncthreads();

    if (tid < NCLASS) {
        const float inv = 1.0f / (redss[0] + redss[1]);
        out[b * NCLASS + tid] = fmaf(redp[tid] + redp[NCLASS + tid], inv, bias[tid]);
    }
}

extern "C" void kernel_launch(void* const* d_in, const int* in_sizes, int n_in,
                              void* d_out, int out_size, void* d_ws, size_t ws_size,
                              hipStream_t stream) {
    const float* x    = (const float*)d_in[0];
    const float* ang  = (const float*)d_in[1];
    const float* W    = (const float*)d_in[2];
    const float* bias = (const float*)d_in[3];
    float* out = (float*)d_out;
    const int batch = in_sizes[0] / FEAT;   // 2048
    qnn_kernel<<<batch, 128, 0, stream>>>(x, ang, W, bias, out);
}